// Round 4
// baseline (942.711 us; speedup 1.0000x reference)
//
#include <hip/hip_runtime.h>

// EdgeConvEncoder R4:
//  - MW=2 per wave (16 cols x 32 edges) -> acc 24 regs -> launch_bounds(512,6)
//    (3 blocks/CU, ~70% occupancy target; was capped at 44% by (512,4))
//  - transposed ctx tile in LDS: epilogue b128 writes, segred b128 reads
//  - everything else (sort, W1/W2 split, async gather, swizzle) from R3

typedef short bf16x8 __attribute__((ext_vector_type(8)));
typedef float f32x4 __attribute__((ext_vector_type(4)));

__device__ __forceinline__ unsigned short f2bf(float f) {
  unsigned int u = __float_as_uint(f);
  u += 0x7FFFu + ((u >> 16) & 1u);  // round-to-nearest-even
  return (unsigned short)(u >> 16);
}

template <int HS>
__device__ __forceinline__ float head_reduce_sum(float v) {
  v += __shfl_xor(v, 1);
  v += __shfl_xor(v, 2);
  v += __shfl_xor(v, 4);
  if (HS == 16) v += __shfl_xor(v, 8);
  return v;
}

// ---------------- weight packing: 6 matrices (W1=top-bot x3, W2=bot x3) ----
__global__ void pack_weights6(const float* __restrict__ wq, const float* __restrict__ wk,
                              const float* __restrict__ wv, unsigned short* __restrict__ dst,
                              int IN, int O) {
  int id = blockIdx.x * blockDim.x + threadIdx.x;
  int kchunks = IN >> 5, nchunks = O >> 4;
  int total = 6 * nchunks * kchunks * 64;
  if (id >= total) return;
  int lane = id & 63;
  int frag = id >> 6;
  int kc = frag % kchunks;
  int nc = (frag / kchunks) % nchunks;
  int mat = frag / (kchunks * nchunks);  // 0..2: W1(q,k,v)  3..5: W2(q,k,v)
  const float* w = (mat % 3 == 0) ? wq : (mat % 3 == 1) ? wk : wv;
  int n = nc * 16 + (lane & 15);
  int k0 = kc * 32 + (lane >> 4) * 8;
  unsigned short tmp[8];
#pragma unroll
  for (int j = 0; j < 8; ++j) {
    int row = k0 + j;
    float bot = w[(size_t)(IN + row) * O + n];
    float val = (mat < 3) ? (w[(size_t)row * O + n] - bot) : bot;
    tmp[j] = f2bf(val);
  }
  uint4 o;
  o.x = (unsigned)tmp[0] | ((unsigned)tmp[1] << 16);
  o.y = (unsigned)tmp[2] | ((unsigned)tmp[3] << 16);
  o.z = (unsigned)tmp[4] | ((unsigned)tmp[5] << 16);
  o.w = (unsigned)tmp[6] | ((unsigned)tmp[7] << 16);
  reinterpret_cast<uint4*>(dst)[id] = o;
}

// ---------------- counting sort by dst ----------------
__global__ void hist3(const int* __restrict__ e0, const int* __restrict__ e1,
                      const int* __restrict__ e2, int E, int* __restrict__ hist, int NP) {
  int i = blockIdx.x * blockDim.x + threadIdx.x;
  if (i >= E) return;
  atomicAdd(&hist[0 * NP + e0[E + i]], 1);
  atomicAdd(&hist[1 * NP + e1[E + i]], 1);
  atomicAdd(&hist[2 * NP + e2[E + i]], 1);
}

__device__ __forceinline__ int block_scan_excl256(int v, int* buf, int t, int* total) {
  buf[t] = v;
  __syncthreads();
#pragma unroll
  for (int off = 1; off < 256; off <<= 1) {
    int add = (t >= off) ? buf[t - off] : 0;
    __syncthreads();
    buf[t] += add;
    __syncthreads();
  }
  int incl = buf[t];
  *total = buf[255];
  __syncthreads();
  return incl - v;
}

__global__ void scan_pass1(const int* __restrict__ hist, int* __restrict__ excl,
                           int* __restrict__ bsum, int n, int NP) {
  __shared__ int buf[256];
  int y = blockIdx.y, t = threadIdx.x;
  int i = blockIdx.x * 256 + t;
  int v = (i < n) ? hist[y * NP + i] : 0;
  int total;
  int ex = block_scan_excl256(v, buf, t, &total);
  if (i < NP) excl[y * NP + i] = ex;
  if (t == 0) bsum[y * 256 + blockIdx.x] = total;
}

__global__ void scan_pass2(int* __restrict__ bsum, int nblk) {
  __shared__ int buf[256];
  int y = blockIdx.y, t = threadIdx.x;
  int v = (t < nblk) ? bsum[y * 256 + t] : 0;
  int total;
  int ex = block_scan_excl256(v, buf, t, &total);
  bsum[y * 256 + t] = ex;
}

__global__ void scan_pass3(const int* __restrict__ excl, const int* __restrict__ bsum,
                           int* __restrict__ rowptr, int n, int NP, int RP, int E) {
  int y = blockIdx.y;
  int i = blockIdx.x * 256 + threadIdx.x;
  if (i < n) rowptr[y * RP + i] = excl[y * NP + i] + bsum[y * 256 + blockIdx.x];
  if (i == 0) rowptr[y * RP + n] = E;
}

__global__ void scatter3(const int* __restrict__ e0, const int* __restrict__ e1,
                         const int* __restrict__ e2, int E, const int* __restrict__ rowptr,
                         int* __restrict__ hist, int* __restrict__ srcS,
                         int* __restrict__ dstS, int NP, int RP) {
  int y = blockIdx.y;
  const int* e = (y == 0) ? e0 : (y == 1) ? e1 : e2;
  int i = blockIdx.x * 256 + threadIdx.x;
  if (i >= E) return;
  int sN = e[i], d = e[E + i];
  int old = atomicSub(&hist[y * NP + d], 1);
  int pos = rowptr[y * RP + d] + old - 1;
  srcS[(size_t)y * E + pos] = sN;
  dstS[(size_t)y * E + pos] = d;
}

// ---------------- fused EdgeConv layer ----------------
// 512 threads = 8 waves. EB edges per block (32 if O=128, 64 if O=64).
// Wave w: col-chunk = w%NCH, edge-half = w/NCH, MW=2 m-tiles -> acc 24 regs.
// q/k/v = xi@W1 + xj@W2 + b; xi rows [0,EB), xj rows [EB,2EB) in swizzled LDS.
// Epilogue writes ctx TRANSPOSED (ctxT[col][edge]) as float4; segmented
// reduction reads float4 runs -> one atomic per (dst-segment x col).
template <int IN, int O, int HS, int EB>
__global__ __launch_bounds__(512, 6) void edge_conv_kernel(
    const unsigned short* __restrict__ xb, const int* __restrict__ srcS,
    const int* __restrict__ dstS, const int E,
    const unsigned short* __restrict__ wpack, const float* __restrict__ bq,
    const float* __restrict__ bk, const float* __restrict__ bv,
    float* __restrict__ s) {
  constexpr int KC = IN / 32;   // 32-elem k-chunks
  constexpr int NCH = O / 16;   // 16-col chunks
  constexpr int CHR = IN / 8;   // 16B chunks per row
  constexpr int CM = CHR - 1;   // swizzle mask
  constexpr int MW = 2;         // m-tiles per wave
  constexpr int EPAD = EB + 4;  // ctxT edge stride
  constexpr float scale = (HS == 16) ? 0.25f : 0.35355339059327373f;

  __shared__ union {
    unsigned short tiles[2 * EB * IN];
    float ctxT[O * EPAD];
  } sm;
  __shared__ int dstL[EB];
  __shared__ float ewL[EB];

  const int t = threadIdx.x;
  const int w = t >> 6;
  const int ln = t & 63;
  const int e0 = blockIdx.x * EB;

  if (t < EB) {
    int eIdx = min(e0 + t, E - 1);
    int sN = srcS[eIdx], dN = dstS[eIdx];
    dstL[t] = dN;
    float dd = fabsf((float)(dN - sN));
    ewL[t] = (dd > 8.0f) ? 1.0f : ((dd == 8.0f) ? 0.0f : -1.0f);
  }

  {  // async gather: 2*EB rows staged across 8 waves
    constexpr int RPI = 64 / CHR;            // rows per instruction
    constexpr int NI = 2 * EB / (RPI * 8);   // instructions per wave
    const int r_in = ln / CHR;
    const int c = ln % CHR;
#pragma unroll
    for (int i = 0; i < NI; ++i) {
      int row = w * (NI * RPI) + i * RPI + r_in;  // 0..2EB-1
      int edge = row & (EB - 1);
      int eIdx = min(e0 + edge, E - 1);
      int node = (row < EB) ? dstS[eIdx] : srcS[eIdx];
      int sc = c ^ (edge & CM);  // stored chunk c holds source chunk sc
      const unsigned short* g = xb + (size_t)node * IN + sc * 8;
      unsigned short* l = &sm.tiles[(size_t)(w * (NI * RPI) + i * RPI) * IN];
      __builtin_amdgcn_global_load_lds(
          (const __attribute__((address_space(1))) unsigned int*)g,
          (__attribute__((address_space(3))) unsigned int*)l, 16, 0, 0);
    }
  }
  __syncthreads();

  const int col = ln & 15;
  const int quad = ln >> 4;
  const int chunkw = w % NCH;
  const int m0 = (w / NCH) * MW;

  f32x4 acc[3][MW];
#pragma unroll
  for (int mat = 0; mat < 3; ++mat)
#pragma unroll
    for (int m = 0; m < MW; ++m) acc[mat][m] = (f32x4){0.f, 0.f, 0.f, 0.f};

#pragma unroll
  for (int kc = 0; kc < KC; ++kc) {
    bf16x8 aI[MW], aJ[MW];
#pragma unroll
    for (int m = 0; m < MW; ++m) {
      int edge = (m0 + m) * 16 + col;
      int sc = (kc * 4 + quad) ^ (edge & CM);  // un-swizzle
      aI[m] = *reinterpret_cast<const bf16x8*>(&sm.tiles[(size_t)edge * IN + sc * 8]);
      aJ[m] = *reinterpret_cast<const bf16x8*>(&sm.tiles[(size_t)(EB + edge) * IN + sc * 8]);
    }
#pragma unroll
    for (int mat = 0; mat < 3; ++mat) {
      const bf16x8 bI = *reinterpret_cast<const bf16x8*>(
          wpack + ((size_t)((mat * NCH + chunkw) * KC + kc) * 64 + ln) * 8);
      const bf16x8 bJ = *reinterpret_cast<const bf16x8*>(
          wpack + ((size_t)(((mat + 3) * NCH + chunkw) * KC + kc) * 64 + ln) * 8);
#pragma unroll
      for (int m = 0; m < MW; ++m) {
        acc[mat][m] = __builtin_amdgcn_mfma_f32_16x16x32_bf16(aI[m], bI, acc[mat][m], 0, 0, 0);
        acc[mat][m] = __builtin_amdgcn_mfma_f32_16x16x32_bf16(aJ[m], bJ, acc[mat][m], 0, 0, 0);
      }
    }
  }
  __syncthreads();  // tiles dead; union becomes ctxT

  // Epilogue: bias + softmax(q*k*scale) + v*ew -> ctxT[col][edge], float4.
  {
    const int colg = chunkw * 16 + col;
    const float bqv = bq[colg], bkv = bk[colg], bvv = bv[colg];
#pragma unroll
    for (int m = 0; m < MW; ++m) {
      const f32x4 qf = acc[0][m];
      const f32x4 kf = acc[1][m];
      const f32x4 vf = acc[2][m];
      f32x4 out;
#pragma unroll
      for (int r = 0; r < 4; ++r) {
        const int eRow = (m0 + m) * 16 + quad * 4 + r;
        float lg = (qf[r] + bqv) * (kf[r] + bkv) * scale;
        float ex = __expf(lg);
        float sum = head_reduce_sum<HS>(ex);
        float val = (ex / sum) * (vf[r] + bvv) * ewL[eRow];
        out[r] = (e0 + eRow < E) ? val : 0.f;
      }
      *reinterpret_cast<f32x4*>(&sm.ctxT[colg * EPAD + (m0 + m) * 16 + quad * 4]) = out;
    }
  }
  __syncthreads();

  // Segmented reduction: thread owns col = t/GRP, 8-edge run; float4 reads.
  {
    constexpr int GRP = 512 / O;       // threads per col
    constexpr int EPT = EB / GRP;      // 8 edges per thread
    static_assert(EPT == 8, "expect 8 edges per thread");
    const int colA = t / GRP;
    const int seg0 = (t % GRP) * 8;
    const float* base = &sm.ctxT[colA * EPAD + seg0];
    f32x4 v0 = *reinterpret_cast<const f32x4*>(base);
    f32x4 v1 = *reinterpret_cast<const f32x4*>(base + 4);
    float run = 0.f;
#pragma unroll
    for (int j = 0; j < 8; ++j) {
      int e = seg0 + j;
      run += (j < 4) ? v0[j] : v1[j - 4];
      bool bound = (j == 7) || (dstL[e + 1] != dstL[e]);
      if (bound) {
        atomicAdd(&s[(size_t)dstL[e] * O + colA], run);
        run = 0.f;
      }
    }
  }
}

// ---------------- conversions / finalize ----------------
__global__ void f32_to_bf16(const float* __restrict__ in, unsigned short* __restrict__ out,
                            int n8) {
  int i = blockIdx.x * blockDim.x + threadIdx.x;
  if (i >= n8) return;
  float4 a = reinterpret_cast<const float4*>(in)[2 * i];
  float4 b = reinterpret_cast<const float4*>(in)[2 * i + 1];
  uint4 o;
  o.x = (unsigned)f2bf(a.x) | ((unsigned)f2bf(a.y) << 16);
  o.y = (unsigned)f2bf(a.z) | ((unsigned)f2bf(a.w) << 16);
  o.z = (unsigned)f2bf(b.x) | ((unsigned)f2bf(b.y) << 16);
  o.w = (unsigned)f2bf(b.z) | ((unsigned)f2bf(b.w) << 16);
  reinterpret_cast<uint4*>(out)[i] = o;
}

__global__ void finalize_relu_f32bf16(float* __restrict__ s, const int* __restrict__ rowptr,
                                      unsigned short* __restrict__ xbo, int total4, int Odiv4) {
  int i = blockIdx.x * blockDim.x + threadIdx.x;
  if (i >= total4) return;
  int node = i / Odiv4;
  float c = fmaxf((float)(rowptr[node + 1] - rowptr[node]), 1.0f);
  float4 v = reinterpret_cast<float4*>(s)[i];
  v.x = fmaxf(v.x / c, 0.f);
  v.y = fmaxf(v.y / c, 0.f);
  v.z = fmaxf(v.z / c, 0.f);
  v.w = fmaxf(v.w / c, 0.f);
  reinterpret_cast<float4*>(s)[i] = v;
  ushort4 o = make_ushort4(f2bf(v.x), f2bf(v.y), f2bf(v.z), f2bf(v.w));
  reinterpret_cast<ushort4*>(xbo)[i] = o;
}

__global__ void finalize_relu_bf16(const float* __restrict__ s, const int* __restrict__ rowptr,
                                   unsigned short* __restrict__ xbo, int total4, int Odiv4) {
  int i = blockIdx.x * blockDim.x + threadIdx.x;
  if (i >= total4) return;
  int node = i / Odiv4;
  float c = fmaxf((float)(rowptr[node + 1] - rowptr[node]), 1.0f);
  float4 v = reinterpret_cast<const float4*>(s)[i];
  ushort4 o = make_ushort4(f2bf(fmaxf(v.x / c, 0.f)), f2bf(fmaxf(v.y / c, 0.f)),
                           f2bf(fmaxf(v.z / c, 0.f)), f2bf(fmaxf(v.w / c, 0.f)));
  reinterpret_cast<ushort4*>(xbo)[i] = o;
}

__global__ void finalize_add_relu(float* __restrict__ out, const float* __restrict__ x0,
                                  const int* __restrict__ rowptr, int total4, int Odiv4) {
  int i = blockIdx.x * blockDim.x + threadIdx.x;
  if (i >= total4) return;
  int node = i / Odiv4;
  float c = fmaxf((float)(rowptr[node + 1] - rowptr[node]), 1.0f);
  float4 v = reinterpret_cast<float4*>(out)[i];
  float4 r = reinterpret_cast<const float4*>(x0)[i];
  v.x = fmaxf(v.x / c + r.x, 0.f);
  v.y = fmaxf(v.y / c + r.y, 0.f);
  v.z = fmaxf(v.z / c + r.z, 0.f);
  v.w = fmaxf(v.w / c + r.w, 0.f);
  reinterpret_cast<float4*>(out)[i] = v;
}

extern "C" void kernel_launch(void* const* d_in, const int* in_sizes, int n_in,
                              void* d_out, int out_size, void* d_ws, size_t ws_size,
                              hipStream_t stream) {
  const float* x = (const float*)d_in[0];
  const int* e0 = (const int*)d_in[1];
  const int* e1 = (const int*)d_in[2];
  const int* e2 = (const int*)d_in[3];
  const float* wq0 = (const float*)d_in[5];
  const float* bq0 = (const float*)d_in[6];
  const float* wk0 = (const float*)d_in[7];
  const float* bk0 = (const float*)d_in[8];
  const float* wv0 = (const float*)d_in[9];
  const float* bv0 = (const float*)d_in[10];
  const float* wq1 = (const float*)d_in[11];
  const float* bq1 = (const float*)d_in[12];
  const float* wk1 = (const float*)d_in[13];
  const float* bk1 = (const float*)d_in[14];
  const float* wv1 = (const float*)d_in[15];
  const float* bv1 = (const float*)d_in[16];
  const float* wq2 = (const float*)d_in[17];
  const float* bq2 = (const float*)d_in[18];
  const float* wk2 = (const float*)d_in[19];
  const float* bk2 = (const float*)d_in[20];
  const float* wv2 = (const float*)d_in[21];
  const float* bv2 = (const float*)d_in[22];

  const int N = in_sizes[0] / 128;  // 50000
  const int E = in_sizes[1] / 2;    // 500000
  const int NBLK = (N + 255) / 256;
  const int NP = NBLK * 256;
  const int RP = NP + 256;

  // ---- workspace carve-up ----
  unsigned short* wp0 = (unsigned short*)d_ws;     // 98304 shorts
  unsigned short* wp1 = wp0 + 98304;               // 49152
  unsigned short* wp2 = wp1 + 49152;               // 49152
  unsigned short* xb0 = wp2 + 49152;               // N*128
  unsigned short* xb1 = xb0 + (size_t)N * 128;     // N*128
  unsigned short* xb2 = xb1 + (size_t)N * 128;     // N*64
  float* s0 = (float*)(xb2 + (size_t)N * 64);      // N*128
  float* s1 = s0 + (size_t)N * 128;                // N*64
  int* hist = (int*)(s1 + (size_t)N * 64);         // 3*NP
  int* excl = hist + 3 * (size_t)NP;               // 3*NP
  int* bsum = excl + 3 * (size_t)NP;               // 3*256
  int* rowptr = bsum + 3 * 256;                    // 3*RP
  int* srcS = rowptr + 3 * (size_t)RP;             // 3*E
  int* dstS = srcS + 3 * (size_t)E;                // 3*E

  hipMemsetAsync(hist, 0, 3 * (size_t)NP * sizeof(int), stream);
  hipMemsetAsync(s0, 0, (size_t)N * 192 * sizeof(float), stream);
  hipMemsetAsync(d_out, 0, (size_t)out_size * sizeof(float), stream);

  pack_weights6<<<48, 256, 0, stream>>>(wq0, wk0, wv0, wp0, 128, 128);
  pack_weights6<<<24, 256, 0, stream>>>(wq1, wk1, wv1, wp1, 128, 64);
  pack_weights6<<<24, 256, 0, stream>>>(wq2, wk2, wv2, wp2, 64, 128);
  f32_to_bf16<<<(N * 16 + 255) / 256, 256, 0, stream>>>(x, xb0, N * 16);

  const int EB256 = (E + 255) / 256;
  hist3<<<EB256, 256, 0, stream>>>(e0, e1, e2, E, hist, NP);
  scan_pass1<<<dim3(NBLK, 3), 256, 0, stream>>>(hist, excl, bsum, N, NP);
  scan_pass2<<<dim3(1, 3), 256, 0, stream>>>(bsum, NBLK);
  scan_pass3<<<dim3(NBLK, 3), 256, 0, stream>>>(excl, bsum, rowptr, N, NP, RP, E);
  scatter3<<<dim3(EB256, 3), 256, 0, stream>>>(e0, e1, e2, E, rowptr, hist, srcS, dstS, NP, RP);

  // L0: IN=128,O=128,HS=16,EB=32 ; L1: IN=128,O=64,HS=8,EB=64 ; L2: IN=64,O=128,HS=16,EB=32
  edge_conv_kernel<128, 128, 16, 32><<<(E + 31) / 32, 512, 0, stream>>>(
      xb0, srcS, dstS, E, wp0, bq0, bk0, bv0, s0);
  finalize_relu_f32bf16<<<(N * 32 + 255) / 256, 256, 0, stream>>>(s0, rowptr, xb1, N * 32, 32);
  edge_conv_kernel<128, 64, 8, 64><<<(E + 63) / 64, 512, 0, stream>>>(
      xb1, srcS + E, dstS + E, E, wp1, bq1, bk1, bv1, s1);
  finalize_relu_bf16<<<(N * 16 + 255) / 256, 256, 0, stream>>>(s1, rowptr + RP, xb2, N * 16, 16);
  edge_conv_kernel<64, 128, 16, 32><<<(E + 31) / 32, 512, 0, stream>>>(
      xb2, srcS + 2 * (size_t)E, dstS + 2 * (size_t)E, E, wp2, bq2, bk2, bv2, (float*)d_out);
  finalize_add_relu<<<(N * 32 + 255) / 256, 256, 0, stream>>>((float*)d_out, s0, rowptr + 2 * RP,
                                                              N * 32, 32);
}

// Round 5
// 647.381 us; speedup vs baseline: 1.4562x; 1.4562x over previous
//
#include <hip/hip_runtime.h>

// EdgeConvEncoder R5: node-level GEMMs + gather-based edge kernel.
//  q_e = Y1q[dst] + Y2q[src],  Y1 = X@(Wtop-Wbot)+bias,  Y2 = X@Wbot
//  -> 10x fewer GEMM FLOPs (50k node rows vs 500k edge rows).
//  Edge kernel: thread = one head of one edge -> thread-local softmax,
//  no shuffles, no MFMA, one barrier; R3-proven segmented reduction.
//  k-scale folded into Wk/bk at pack time; biases folded into Y1.

typedef short bf16x8 __attribute__((ext_vector_type(8)));
typedef float f32x4 __attribute__((ext_vector_type(4)));

__device__ __forceinline__ unsigned short f2bf(float f) {
  unsigned int u = __float_as_uint(f);
  u += 0x7FFFu + ((u >> 16) & 1u);  // round-to-nearest-even
  return (unsigned short)(u >> 16);
}
__device__ __forceinline__ float b2f(short s) {
  return __uint_as_float(((unsigned)(unsigned short)s) << 16);
}

// ---------------- weight packing: 6 matrices (W1=top-bot x3, W2=bot x3) ----
// k-scale folded into mats 1 and 4 (the k matrices).
__global__ void pack_weights6(const float* __restrict__ wq, const float* __restrict__ wk,
                              const float* __restrict__ wv, unsigned short* __restrict__ dst,
                              int IN, int O, float kscale) {
  int id = blockIdx.x * blockDim.x + threadIdx.x;
  int kchunks = IN >> 5, nchunks = O >> 4;
  int total = 6 * nchunks * kchunks * 64;
  if (id >= total) return;
  int lane = id & 63;
  int frag = id >> 6;
  int kc = frag % kchunks;
  int nc = (frag / kchunks) % nchunks;
  int mat = frag / (kchunks * nchunks);  // 0..2: W1(q,k,v)  3..5: W2(q,k,v)
  const float* w = (mat % 3 == 0) ? wq : (mat % 3 == 1) ? wk : wv;
  float mul = (mat % 3 == 1) ? kscale : 1.0f;
  int n = nc * 16 + (lane & 15);
  int k0 = kc * 32 + (lane >> 4) * 8;
  unsigned short tmp[8];
#pragma unroll
  for (int j = 0; j < 8; ++j) {
    int row = k0 + j;
    float bot = w[(size_t)(IN + row) * O + n];
    float val = (mat < 3) ? (w[(size_t)row * O + n] - bot) : bot;
    tmp[j] = f2bf(val * mul);
  }
  uint4 o;
  o.x = (unsigned)tmp[0] | ((unsigned)tmp[1] << 16);
  o.y = (unsigned)tmp[2] | ((unsigned)tmp[3] << 16);
  o.z = (unsigned)tmp[4] | ((unsigned)tmp[5] << 16);
  o.w = (unsigned)tmp[6] | ((unsigned)tmp[7] << 16);
  reinterpret_cast<uint4*>(dst)[id] = o;
}

// bias6[mat*O + c]: q->bq, k->bk*kscale, v->bv, mats 3..5 -> 0
__global__ void pack_bias(const float* __restrict__ bq, const float* __restrict__ bk,
                          const float* __restrict__ bv, float kscale, int O,
                          float* __restrict__ out) {
  int i = blockIdx.x * blockDim.x + threadIdx.x;
  if (i >= 6 * O) return;
  int mat = i / O, c = i % O;
  float v = 0.f;
  if (mat == 0) v = bq[c];
  else if (mat == 1) v = bk[c] * kscale;
  else if (mat == 2) v = bv[c];
  out[i] = v;
}

// ---------------- counting sort by dst ----------------
__global__ void hist3(const int* __restrict__ e0, const int* __restrict__ e1,
                      const int* __restrict__ e2, int E, int* __restrict__ hist, int NP) {
  int i = blockIdx.x * blockDim.x + threadIdx.x;
  if (i >= E) return;
  atomicAdd(&hist[0 * NP + e0[E + i]], 1);
  atomicAdd(&hist[1 * NP + e1[E + i]], 1);
  atomicAdd(&hist[2 * NP + e2[E + i]], 1);
}

__device__ __forceinline__ int block_scan_excl256(int v, int* buf, int t, int* total) {
  buf[t] = v;
  __syncthreads();
#pragma unroll
  for (int off = 1; off < 256; off <<= 1) {
    int add = (t >= off) ? buf[t - off] : 0;
    __syncthreads();
    buf[t] += add;
    __syncthreads();
  }
  int incl = buf[t];
  *total = buf[255];
  __syncthreads();
  return incl - v;
}

__global__ void scan_pass1(const int* __restrict__ hist, int* __restrict__ excl,
                           int* __restrict__ bsum, int n, int NP) {
  __shared__ int buf[256];
  int y = blockIdx.y, t = threadIdx.x;
  int i = blockIdx.x * 256 + t;
  int v = (i < n) ? hist[y * NP + i] : 0;
  int total;
  int ex = block_scan_excl256(v, buf, t, &total);
  if (i < NP) excl[y * NP + i] = ex;
  if (t == 0) bsum[y * 256 + blockIdx.x] = total;
}

__global__ void scan_pass2(int* __restrict__ bsum, int nblk) {
  __shared__ int buf[256];
  int y = blockIdx.y, t = threadIdx.x;
  int v = (t < nblk) ? bsum[y * 256 + t] : 0;
  int total;
  int ex = block_scan_excl256(v, buf, t, &total);
  bsum[y * 256 + t] = ex;
}

__global__ void scan_pass3(const int* __restrict__ excl, const int* __restrict__ bsum,
                           int* __restrict__ rowptr, int n, int NP, int RP, int E) {
  int y = blockIdx.y;
  int i = blockIdx.x * 256 + threadIdx.x;
  if (i < n) rowptr[y * RP + i] = excl[y * NP + i] + bsum[y * 256 + blockIdx.x];
  if (i == 0) rowptr[y * RP + n] = E;
}

__global__ void scatter3(const int* __restrict__ e0, const int* __restrict__ e1,
                         const int* __restrict__ e2, int E, const int* __restrict__ rowptr,
                         int* __restrict__ hist, int* __restrict__ srcS,
                         int* __restrict__ dstS, int NP, int RP) {
  int y = blockIdx.y;
  const int* e = (y == 0) ? e0 : (y == 1) ? e1 : e2;
  int i = blockIdx.x * 256 + threadIdx.x;
  if (i >= E) return;
  int sN = e[i], d = e[E + i];
  int old = atomicSub(&hist[y * NP + d], 1);
  int pos = rowptr[y * RP + d] + old - 1;
  srcS[(size_t)y * E + pos] = sN;
  dstS[(size_t)y * E + pos] = d;
}

// ---------------- node-level GEMM: Y1 = X@W1 + bias, Y2 = X@W2 (bf16 out) ---
// Block 256 thr / 4 waves, 64 nodes x 128 cols (wave = 2 gchunks x 4 m-tiles).
// Y layout: [node][3*O] = [q | k | v] contiguous per node.
template <int IN, int O>
__global__ __launch_bounds__(256, 4) void node_gemm(
    const unsigned short* __restrict__ xb, int N,
    const unsigned short* __restrict__ wpack, const float* __restrict__ bias6,
    unsigned short* __restrict__ Y1, unsigned short* __restrict__ Y2) {
  constexpr int KC = IN / 32;
  constexpr int NCH = O / 16;
  constexpr int CHR = IN / 8;
  constexpr int CM = CHR - 1;
  __shared__ unsigned short tiles[64 * IN];

  const int t = threadIdx.x, w = t >> 6, ln = t & 63;
  const int n0 = blockIdx.x * 64;

  {  // stage 64 node rows (consecutive) with XOR chunk swizzle
    constexpr int RPI = 64 / CHR;
    constexpr int NI = 16 / RPI;
    const int r_in = ln / CHR, c = ln % CHR;
#pragma unroll
    for (int i = 0; i < NI; ++i) {
      int row = w * 16 + i * RPI + r_in;
      int node = min(n0 + row, N - 1);
      int sc = c ^ (row & CM);
      const unsigned short* g = xb + (size_t)node * IN + sc * 8;
      unsigned short* l = &tiles[(size_t)(w * 16 + i * RPI) * IN];
      __builtin_amdgcn_global_load_lds(
          (const __attribute__((address_space(1))) unsigned int*)g,
          (__attribute__((address_space(3))) unsigned int*)l, 16, 0, 0);
    }
  }
  __syncthreads();

  const int col = ln & 15, quad = ln >> 4;
  const int g0 = blockIdx.y * 8 + w * 2;  // gchunk = mat*NCH + nc

  f32x4 acc[2][4];
#pragma unroll
  for (int cc = 0; cc < 2; ++cc)
#pragma unroll
    for (int m = 0; m < 4; ++m) acc[cc][m] = (f32x4){0.f, 0.f, 0.f, 0.f};

#pragma unroll
  for (int kc = 0; kc < KC; ++kc) {
    bf16x8 a[4];
#pragma unroll
    for (int m = 0; m < 4; ++m) {
      int row = m * 16 + col;
      int sc = (kc * 4 + quad) ^ (row & CM);
      a[m] = *reinterpret_cast<const bf16x8*>(&tiles[(size_t)row * IN + sc * 8]);
    }
#pragma unroll
    for (int cc = 0; cc < 2; ++cc) {
      const bf16x8 b = *reinterpret_cast<const bf16x8*>(
          wpack + ((size_t)((g0 + cc) * KC + kc) * 64 + ln) * 8);
#pragma unroll
      for (int m = 0; m < 4; ++m)
        acc[cc][m] = __builtin_amdgcn_mfma_f32_16x16x32_bf16(a[m], b, acc[cc][m], 0, 0, 0);
    }
  }

#pragma unroll
  for (int cc = 0; cc < 2; ++cc) {
    int gch = g0 + cc;
    int mat = gch / NCH, ncg = gch % NCH;
    unsigned short* Yp = (mat < 3) ? Y1 : Y2;
    int mo = (mat < 3) ? mat : mat - 3;
    float bv = bias6[gch * 16 + col];
    size_t coloff = (size_t)mo * O + ncg * 16 + col;
#pragma unroll
    for (int m = 0; m < 4; ++m)
#pragma unroll
      for (int r = 0; r < 4; ++r) {
        int node = n0 + m * 16 + quad * 4 + r;
        if (node < N) Yp[(size_t)node * (3 * O) + coloff] = f2bf(acc[cc][m][r] + bv);
      }
  }
}

// ---------------- gather-based edge kernel ----------------
// 512 threads, 64 edges, 8 threads/edge, thread = one head (HS channels).
// q = Y1q[dst]+Y2q[src] etc (bias/scale pre-folded). Thread-local softmax.
// ctx -> LDS in chunk-rotated layout (2-way banks), then R3-style segred.
template <int O, int HS>
__global__ __launch_bounds__(512, 6) void edge_attn_kernel(
    const unsigned short* __restrict__ Y1, const unsigned short* __restrict__ Y2,
    const int* __restrict__ srcS, const int* __restrict__ dstS, const int E,
    float* __restrict__ s) {
  constexpr int NL = HS / 8;     // bf16x8 loads per matrix
  constexpr int PM = O / 4 - 1;  // LDS chunk mask
  __shared__ float ctx[64 * O];
  __shared__ int dstL[64];

  const int t = threadIdx.x;
  const int e = t >> 3, head = t & 7;
  const int eG = blockIdx.x * 64 + e;
  const int eC = min(eG, E - 1);
  const bool valid = eG < E;
  const int sN = srcS[eC], dN = dstS[eC];
  if ((t & 7) == 0) dstL[e] = dN;
  const float dd = fabsf((float)(dN - sN));
  const float ew = (dd > 8.f) ? 1.f : ((dd == 8.f) ? 0.f : -1.f);

  const unsigned short* b1 = Y1 + (size_t)dN * (3 * O) + head * HS;
  const unsigned short* b2 = Y2 + (size_t)sN * (3 * O) + head * HS;

  float ex[HS];
  float sum = 0.f;
#pragma unroll
  for (int l = 0; l < NL; ++l) {
    bf16x8 q1 = *reinterpret_cast<const bf16x8*>(b1 + l * 8);
    bf16x8 q2 = *reinterpret_cast<const bf16x8*>(b2 + l * 8);
    bf16x8 k1 = *reinterpret_cast<const bf16x8*>(b1 + O + l * 8);
    bf16x8 k2 = *reinterpret_cast<const bf16x8*>(b2 + O + l * 8);
#pragma unroll
    for (int j = 0; j < 8; ++j) {
      float q = b2f(q1[j]) + b2f(q2[j]);
      float k = b2f(k1[j]) + b2f(k2[j]);
      float eo = __expf(q * k);  // scale folded into k
      ex[l * 8 + j] = eo;
      sum += eo;
    }
  }
  const float rs = ew / sum;
#pragma unroll
  for (int l = 0; l < NL; ++l) {
    bf16x8 v1 = *reinterpret_cast<const bf16x8*>(b1 + 2 * O + l * 8);
    bf16x8 v2 = *reinterpret_cast<const bf16x8*>(b2 + 2 * O + l * 8);
#pragma unroll
    for (int g2 = 0; g2 < 2; ++g2) {
      f32x4 o;
#pragma unroll
      for (int j2 = 0; j2 < 4; ++j2) {
        int j = g2 * 4 + j2;
        float v = b2f(v1[j]) + b2f(v2[j]);
        o[j2] = valid ? ex[l * 8 + j] * rs * v : 0.f;
      }
      int g = l * 2 + g2;                   // chunk-in-head
      int p = (g * 8 + head + e) & PM;      // rotated chunk position
      *reinterpret_cast<f32x4*>(&ctx[e * O + p * 4]) = o;
    }
  }
  __syncthreads();

  // segred: col = head*HS + c (bit-spread so a wave covers all heads)
  {
    constexpr int GRP = 512 / O;
    constexpr int EPT = 64 / GRP;
    const int hs2 = t & 7;
    const int cs = (t >> 3) & (HS - 1);
    const int colA = hs2 * HS + cs;
    const int seg0 = (t / O) * EPT;
    const int inv = (cs >> 2) * 8 + hs2;
    const int js = cs & 3;
    float run = 0.f;
#pragma unroll
    for (int i = 0; i < EPT; ++i) {
      int ee = seg0 + i;
      int p = (inv + ee) & PM;
      run += ctx[ee * O + p * 4 + js];
      bool bound = (i == EPT - 1) || (dstL[ee + 1] != dstL[ee]);
      if (bound) {
        atomicAdd(&s[(size_t)dstL[ee] * O + colA], run);
        run = 0.f;
      }
    }
  }
}

// ---------------- conversions / finalize ----------------
__global__ void f32_to_bf16(const float* __restrict__ in, unsigned short* __restrict__ out,
                            int n8) {
  int i = blockIdx.x * blockDim.x + threadIdx.x;
  if (i >= n8) return;
  float4 a = reinterpret_cast<const float4*>(in)[2 * i];
  float4 b = reinterpret_cast<const float4*>(in)[2 * i + 1];
  uint4 o;
  o.x = (unsigned)f2bf(a.x) | ((unsigned)f2bf(a.y) << 16);
  o.y = (unsigned)f2bf(a.z) | ((unsigned)f2bf(a.w) << 16);
  o.z = (unsigned)f2bf(b.x) | ((unsigned)f2bf(b.y) << 16);
  o.w = (unsigned)f2bf(b.z) | ((unsigned)f2bf(b.w) << 16);
  reinterpret_cast<uint4*>(out)[i] = o;
}

__global__ void finalize_relu_f32bf16(float* __restrict__ s, const int* __restrict__ rowptr,
                                      unsigned short* __restrict__ xbo, int total4, int Odiv4) {
  int i = blockIdx.x * blockDim.x + threadIdx.x;
  if (i >= total4) return;
  int node = i / Odiv4;
  float c = fmaxf((float)(rowptr[node + 1] - rowptr[node]), 1.0f);
  float4 v = reinterpret_cast<float4*>(s)[i];
  v.x = fmaxf(v.x / c, 0.f);
  v.y = fmaxf(v.y / c, 0.f);
  v.z = fmaxf(v.z / c, 0.f);
  v.w = fmaxf(v.w / c, 0.f);
  reinterpret_cast<float4*>(s)[i] = v;
  ushort4 o = make_ushort4(f2bf(v.x), f2bf(v.y), f2bf(v.z), f2bf(v.w));
  reinterpret_cast<ushort4*>(xbo)[i] = o;
}

__global__ void finalize_relu_bf16(const float* __restrict__ s, const int* __restrict__ rowptr,
                                   unsigned short* __restrict__ xbo, int total4, int Odiv4) {
  int i = blockIdx.x * blockDim.x + threadIdx.x;
  if (i >= total4) return;
  int node = i / Odiv4;
  float c = fmaxf((float)(rowptr[node + 1] - rowptr[node]), 1.0f);
  float4 v = reinterpret_cast<const float4*>(s)[i];
  ushort4 o = make_ushort4(f2bf(fmaxf(v.x / c, 0.f)), f2bf(fmaxf(v.y / c, 0.f)),
                           f2bf(fmaxf(v.z / c, 0.f)), f2bf(fmaxf(v.w / c, 0.f)));
  reinterpret_cast<ushort4*>(xbo)[i] = o;
}

__global__ void finalize_add_relu(float* __restrict__ out, const float* __restrict__ x0,
                                  const int* __restrict__ rowptr, int total4, int Odiv4) {
  int i = blockIdx.x * blockDim.x + threadIdx.x;
  if (i >= total4) return;
  int node = i / Odiv4;
  float c = fmaxf((float)(rowptr[node + 1] - rowptr[node]), 1.0f);
  float4 v = reinterpret_cast<float4*>(out)[i];
  float4 r = reinterpret_cast<const float4*>(x0)[i];
  v.x = fmaxf(v.x / c + r.x, 0.f);
  v.y = fmaxf(v.y / c + r.y, 0.f);
  v.z = fmaxf(v.z / c + r.z, 0.f);
  v.w = fmaxf(v.w / c + r.w, 0.f);
  reinterpret_cast<float4*>(out)[i] = v;
}

extern "C" void kernel_launch(void* const* d_in, const int* in_sizes, int n_in,
                              void* d_out, int out_size, void* d_ws, size_t ws_size,
                              hipStream_t stream) {
  const float* x = (const float*)d_in[0];
  const int* e0 = (const int*)d_in[1];
  const int* e1 = (const int*)d_in[2];
  const int* e2 = (const int*)d_in[3];
  const float* wq0 = (const float*)d_in[5];
  const float* bq0 = (const float*)d_in[6];
  const float* wk0 = (const float*)d_in[7];
  const float* bk0 = (const float*)d_in[8];
  const float* wv0 = (const float*)d_in[9];
  const float* bv0 = (const float*)d_in[10];
  const float* wq1 = (const float*)d_in[11];
  const float* bq1 = (const float*)d_in[12];
  const float* wk1 = (const float*)d_in[13];
  const float* bk1 = (const float*)d_in[14];
  const float* wv1 = (const float*)d_in[15];
  const float* bv1 = (const float*)d_in[16];
  const float* wq2 = (const float*)d_in[17];
  const float* bq2 = (const float*)d_in[18];
  const float* wk2 = (const float*)d_in[19];
  const float* bk2 = (const float*)d_in[20];
  const float* wv2 = (const float*)d_in[21];
  const float* bv2 = (const float*)d_in[22];

  const int N = in_sizes[0] / 128;  // 50000
  const int E = in_sizes[1] / 2;    // 500000
  const int NBLK = (N + 255) / 256;
  const int NP = NBLK * 256;
  const int RP = NP + 256;
  const float SC16 = 0.25f;                 // 1/sqrt(16)
  const float SC8 = 0.35355339059327373f;   // 1/sqrt(8)

  // ---- workspace carve-up (~143 MB) ----
  unsigned short* wp0 = (unsigned short*)d_ws;       // 98304 shorts
  unsigned short* wp1 = wp0 + 98304;                 // 49152
  unsigned short* wp2 = wp1 + 49152;                 // 49152
  float* bias0 = (float*)(wp2 + 49152);              // 768
  float* bias1 = bias0 + 768;                        // 384
  float* bias2 = bias1 + 384;                        // 768
  unsigned short* xb = (unsigned short*)(bias2 + 768);  // N*128 (reused)
  unsigned short* Y1 = xb + (size_t)N * 128;         // N*384
  unsigned short* Y2 = Y1 + (size_t)N * 384;         // N*384
  float* s0 = (float*)(Y2 + (size_t)N * 384);        // N*128
  float* s1 = s0 + (size_t)N * 128;                  // N*64
  int* hist = (int*)(s1 + (size_t)N * 64);           // 3*NP
  int* excl = hist + 3 * (size_t)NP;                 // 3*NP
  int* bsum = excl + 3 * (size_t)NP;                 // 768
  int* rowptr = bsum + 768;                          // 3*RP
  int* srcS = rowptr + 3 * (size_t)RP;               // 3*E
  int* dstS = srcS + 3 * (size_t)E;                  // 3*E

  hipMemsetAsync(hist, 0, 3 * (size_t)NP * sizeof(int), stream);
  hipMemsetAsync(s0, 0, (size_t)N * 192 * sizeof(float), stream);
  hipMemsetAsync(d_out, 0, (size_t)out_size * sizeof(float), stream);

  pack_weights6<<<48, 256, 0, stream>>>(wq0, wk0, wv0, wp0, 128, 128, SC16);
  pack_weights6<<<24, 256, 0, stream>>>(wq1, wk1, wv1, wp1, 128, 64, SC8);
  pack_weights6<<<24, 256, 0, stream>>>(wq2, wk2, wv2, wp2, 64, 128, SC16);
  pack_bias<<<3, 256, 0, stream>>>(bq0, bk0, bv0, SC16, 128, bias0);
  pack_bias<<<2, 256, 0, stream>>>(bq1, bk1, bv1, SC8, 64, bias1);
  pack_bias<<<3, 256, 0, stream>>>(bq2, bk2, bv2, SC16, 128, bias2);
  f32_to_bf16<<<(N * 16 + 255) / 256, 256, 0, stream>>>(x, xb, N * 16);

  const int EB256 = (E + 255) / 256;
  hist3<<<EB256, 256, 0, stream>>>(e0, e1, e2, E, hist, NP);
  scan_pass1<<<dim3(NBLK, 3), 256, 0, stream>>>(hist, excl, bsum, N, NP);
  scan_pass2<<<dim3(1, 3), 256, 0, stream>>>(bsum, NBLK);
  scan_pass3<<<dim3(NBLK, 3), 256, 0, stream>>>(excl, bsum, rowptr, N, NP, RP, E);
  scatter3<<<dim3(EB256, 3), 256, 0, stream>>>(e0, e1, e2, E, rowptr, hist, srcS, dstS, NP, RP);

  const int NT = (N + 63) / 64;
  const int EBK = (E + 63) / 64;

  // Layer 0: IN=128, O=128, HS=16
  node_gemm<128, 128><<<dim3(NT, 6), 256, 0, stream>>>(xb, N, wp0, bias0, Y1, Y2);
  edge_attn_kernel<128, 16><<<EBK, 512, 0, stream>>>(Y1, Y2, srcS, dstS, E, s0);
  finalize_relu_f32bf16<<<(N * 32 + 255) / 256, 256, 0, stream>>>(s0, rowptr, xb, N * 32, 32);
  // Layer 1: IN=128, O=64, HS=8
  node_gemm<128, 64><<<dim3(NT, 3), 256, 0, stream>>>(xb, N, wp1, bias1, Y1, Y2);
  edge_attn_kernel<64, 8><<<EBK, 512, 0, stream>>>(Y1, Y2, srcS + E, dstS + E, E, s1);
  finalize_relu_bf16<<<(N * 16 + 255) / 256, 256, 0, stream>>>(s1, rowptr + RP, xb, N * 16, 16);
  // Layer 2: IN=64, O=128, HS=16 -> accumulate into d_out
  node_gemm<64, 128><<<dim3(NT, 6), 256, 0, stream>>>(xb, N, wp2, bias2, Y1, Y2);
  edge_attn_kernel<128, 16><<<EBK, 512, 0, stream>>>(Y1, Y2, srcS + 2 * (size_t)E,
                                                     dstS + 2 * (size_t)E, E, (float*)d_out);
  finalize_add_relu<<<(N * 32 + 255) / 256, 256, 0, stream>>>((float*)d_out, s0, rowptr + 2 * RP,
                                                              N * 32, 32);
}